// Round 1
// baseline (70.392 us; speedup 1.0000x reference)
//
#include <hip/hip_runtime.h>

#define N_CP   128
#define N_DATA 32768
#define BATCH  16
#define DIM    3

// One thread per (b, n). Exploits the 5-wide band structure of the NURBS
// basis matrix: column n is nonzero only on rows [span-4, span],
// span = clip(4 + floor(124*n/32767), 4, 127). We read a 7-row window
// [span-5, span+1] to be robust to +/-1 rounding mismatch vs the
// reference's float64 searchsorted at exact knot crossings; out-of-band
// entries are exactly 0.0f so they contribute nothing.
__global__ __launch_bounds__(256) void nurbs_band_kernel(
    const float* __restrict__ cp,    // [BATCH, DIM, N_CP]
    const float* __restrict__ w,     // [BATCH, 1, N_CP]
    const float* __restrict__ Nmat,  // [N_CP, N_DATA]
    float* __restrict__ out)         // [BATCH, DIM, N_DATA]
{
    __shared__ float w_l[N_CP];
    __shared__ float cw_l[DIM][N_CP];

    const int tid = blockIdx.x * 256 + threadIdx.x;
    const int b = tid >> 15;            // N_DATA = 2^15, block has single b
    const int n = tid & (N_DATA - 1);

    // Stage w[b,:] and cw[d][c] = cp[b,d,c]*w[b,c] into LDS (2 KB).
    const int t = threadIdx.x;
    if (t < N_CP) {
        float wv = w[b * N_CP + t];
        w_l[t] = wv;
#pragma unroll
        for (int d = 0; d < DIM; ++d)
            cw_l[d][t] = cp[(b * DIM + d) * N_CP + t] * wv;
    }
    __syncthreads();

    // Band window: rows lo..lo+6, guaranteed to cover all nonzeros of col n.
    float x = (float)n * (124.0f / 32767.0f);
    int span = 4 + (int)x;              // x >= 0, (int) == floor
    if (span > 127) span = 127;
    int lo = span - 5;
    if (lo < 0)   lo = 0;
    if (lo > 121) lo = 121;             // keep lo+6 <= 127

    float W = 0.0f, s0 = 0.0f, s1 = 0.0f, s2 = 0.0f;
    const float* col = Nmat + n;
#pragma unroll
    for (int r = 0; r < 7; ++r) {
        const int c = lo + r;
        const float Nv = col[(size_t)c * N_DATA];  // coalesced across lanes
        W  = fmaf(w_l[c],     Nv, W);
        s0 = fmaf(cw_l[0][c], Nv, s0);
        s1 = fmaf(cw_l[1][c], Nv, s1);
        s2 = fmaf(cw_l[2][c], Nv, s2);
    }

    const float inv = 1.0f / W;
    float* ob = out + (size_t)b * (DIM * N_DATA) + n;
    ob[0]          = s0 * inv;
    ob[N_DATA]     = s1 * inv;
    ob[2 * N_DATA] = s2 * inv;
}

extern "C" void kernel_launch(void* const* d_in, const int* in_sizes, int n_in,
                              void* d_out, int out_size, void* d_ws, size_t ws_size,
                              hipStream_t stream) {
    // d_in[0] = input (unused by reference), d_in[1] = control_points,
    // d_in[2] = weights, d_in[3] = N
    const float* cp   = (const float*)d_in[1];
    const float* w    = (const float*)d_in[2];
    const float* Nmat = (const float*)d_in[3];
    float* out = (float*)d_out;

    const int total = BATCH * N_DATA;           // 524288 threads
    const int blocks = total / 256;             // 2048 blocks
    nurbs_band_kernel<<<blocks, 256, 0, stream>>>(cp, w, Nmat, out);
}